// Round 2
// baseline (319.193 us; speedup 1.0000x reference)
//
#include <hip/hip_runtime.h>
#include <math.h>

// SPAIRPointFeatureNetwork on MI355X.
// Algebraic restructure: for each layer,
//   h_{p,j} = msg @ wa + ba = Q[j] - G[p],  Q[j]=x_j@wa_x + pos_j@wa_p + ba, G[p]=pos_p@wa_p
// celu monotonic => segment_max(celu(h)) = celu(max_j Q[j] - G[p]).
// So per-edge work = gather Q row + running max. All matmuls become O(N) precomputes.
//
// NOTE (R1 post-mortem): harness delivers integer inputs as int32 ("integer ->
// const int*") regardless of reference int64 dtype. Reading in_index as int64
// faulted. Use const int* directly — no conversion pass needed.

#define NPTS 65536
#define KNBR 64

__device__ __forceinline__ float celu1(float x) {
    return x > 0.0f ? x : (__expf(x) - 1.0f);
}

// Kernel 1: compute Q1 from pos, copy pos to d_out, zero the batch tail.
__global__ __launch_bounds__(256) void k_prep1(
    const float* __restrict__ pos,
    const float* __restrict__ w1a,   // 6 x 8
    const float* __restrict__ b1a,   // 8
    float* __restrict__ q1,          // N x 8
    float* __restrict__ dout,
    int out_size)
{
    int t = blockIdx.x * 256 + threadIdx.x;
    if (t >= NPTS) return;
    float p0 = pos[3 * t + 0];
    float p1 = pos[3 * t + 1];
    float p2 = pos[3 * t + 2];
    // output 0: pos copy
    dout[3 * t + 0] = p0;
    dout[3 * t + 1] = p1;
    dout[3 * t + 2] = p2;
    // Q1[c] = b1a[c] + sum_f pos[f]*(w1a[f][c] + w1a[3+f][c])   (x == pos for layer 1)
#pragma unroll
    for (int c = 0; c < 8; ++c) {
        float q = b1a[c];
        q = fmaf(p0, w1a[0 * 8 + c] + w1a[3 * 8 + c], q);
        q = fmaf(p1, w1a[1 * 8 + c] + w1a[4 * 8 + c], q);
        q = fmaf(p2, w1a[2 * 8 + c] + w1a[5 * 8 + c], q);
        q1[8 * t + c] = q;
    }
    // output 2: batch (all zeros). Cover whatever tail layout the harness uses.
    for (int j = 35 * NPTS + t; j < out_size; j += NPTS)
        dout[j] = 0.0f;
}

// Edge kernel: per point, max over 64 gathered Q rows. 8 threads (slices) per
// point -> 8192 waves total (8 waves/SIMD) to hide gather latency.
template <int FH>
__global__ __launch_bounds__(256) void k_edge(
    const float* __restrict__ q,    // N x FH
    const int* __restrict__ idx,    // N x 64 (int32)
    float* __restrict__ m)          // N x FH (segment max of Q)
{
    int gt = blockIdx.x * 256 + threadIdx.x;
    int p = gt >> 3;
    int s = gt & 7;
    float mx[FH];
#pragma unroll
    for (int c = 0; c < FH; ++c) mx[c] = -3.0e38f;

    int base = p * KNBR + s;
#pragma unroll 2
    for (int e = 0; e < KNBR / 8; ++e) {
        int j = idx[base + e * 8];
        const float4* qr = (const float4*)(q + j * FH);
#pragma unroll
        for (int c4 = 0; c4 < FH / 4; ++c4) {
            float4 v = qr[c4];
            mx[4 * c4 + 0] = fmaxf(mx[4 * c4 + 0], v.x);
            mx[4 * c4 + 1] = fmaxf(mx[4 * c4 + 1], v.y);
            mx[4 * c4 + 2] = fmaxf(mx[4 * c4 + 2], v.z);
            mx[4 * c4 + 3] = fmaxf(mx[4 * c4 + 3], v.w);
        }
    }
    // butterfly max across the 8 slices of this point (lanes 8p..8p+7 are
    // contiguous; strides 1,2,4 stay within the group)
#pragma unroll
    for (int st = 1; st < 8; st <<= 1) {
#pragma unroll
        for (int c = 0; c < FH; ++c)
            mx[c] = fmaxf(mx[c], __shfl_xor(mx[c], st, 64));
    }
    // slice s stores channels [s*CW, (s+1)*CW). Compile-time mux (runtime
    // indexing of mx[] would spill to scratch).
    constexpr int CW = FH / 8;
    float outv[CW];
#pragma unroll
    for (int c = 0; c < CW; ++c) {
        float v = mx[c];
#pragma unroll
        for (int g = 1; g < 8; ++g)
            v = (s == g) ? mx[g * CW + c] : v;
        outv[c] = v;
    }
    float* dst = m + p * FH + s * CW;
    if constexpr (CW == 4) {
        *(float4*)dst = make_float4(outv[0], outv[1], outv[2], outv[3]);
    } else if constexpr (CW == 2) {
        *(float2*)dst = make_float2(outv[0], outv[1]);
    } else {
        *dst = outv[0];
    }
}

// Finish kernel: agg = celu(m - G), x = celu(agg@wb + bb); optionally emit
// next layer's Q (fused, so x never hits memory except the final layer).
template <int FH, int FOUT, int FHN, bool WRITEX>
__global__ __launch_bounds__(256) void k_finish(
    const float* __restrict__ m,     // N x FH
    const float* __restrict__ pos,
    const float* __restrict__ wap,   // 3 x FH  (dpos rows of this layer's wa)
    const float* __restrict__ wb,    // FH x FOUT
    const float* __restrict__ bb,    // FOUT
    const float* __restrict__ wan,   // (FOUT+3) x FHN (next layer wa) or null
    const float* __restrict__ ban,   // FHN or null
    float* __restrict__ xout,        // N x FOUT (only if WRITEX)
    float* __restrict__ qnext)       // N x FHN (only if FHN>0)
{
    int t = blockIdx.x * 256 + threadIdx.x;
    float p0 = pos[3 * t + 0];
    float p1 = pos[3 * t + 1];
    float p2 = pos[3 * t + 2];

    float h[FH];
    const float4* mr = (const float4*)(m + t * FH);
#pragma unroll
    for (int c4 = 0; c4 < FH / 4; ++c4) {
        float4 v = mr[c4];
        h[4 * c4 + 0] = v.x;
        h[4 * c4 + 1] = v.y;
        h[4 * c4 + 2] = v.z;
        h[4 * c4 + 3] = v.w;
    }
#pragma unroll
    for (int c = 0; c < FH; ++c) {
        float g = p0 * wap[c] + p1 * wap[FH + c] + p2 * wap[2 * FH + c];
        h[c] = celu1(h[c] - g);
    }
    float x[FOUT];
#pragma unroll
    for (int c2 = 0; c2 < FOUT; ++c2) {
        float a = bb[c2];
#pragma unroll
        for (int c = 0; c < FH; ++c)
            a = fmaf(h[c], wb[c * FOUT + c2], a);
        x[c2] = celu1(a);
    }
    if constexpr (WRITEX) {
        float4* xo = (float4*)(xout + t * FOUT);
#pragma unroll
        for (int c4 = 0; c4 < FOUT / 4; ++c4)
            xo[c4] = make_float4(x[4 * c4 + 0], x[4 * c4 + 1], x[4 * c4 + 2], x[4 * c4 + 3]);
    }
    if constexpr (FHN > 0) {
        float qn[FHN];
#pragma unroll
        for (int cn = 0; cn < FHN; ++cn) {
            float a = ban[cn];
#pragma unroll
            for (int c2 = 0; c2 < FOUT; ++c2)
                a = fmaf(x[c2], wan[c2 * FHN + cn], a);
            a = fmaf(p0, wan[(FOUT + 0) * FHN + cn], a);
            a = fmaf(p1, wan[(FOUT + 1) * FHN + cn], a);
            a = fmaf(p2, wan[(FOUT + 2) * FHN + cn], a);
            qn[cn] = a;
        }
        float4* qo = (float4*)(qnext + t * FHN);
#pragma unroll
        for (int cn4 = 0; cn4 < FHN / 4; ++cn4)
            qo[cn4] = make_float4(qn[4 * cn4 + 0], qn[4 * cn4 + 1], qn[4 * cn4 + 2], qn[4 * cn4 + 3]);
    }
}

extern "C" void kernel_launch(void* const* d_in, const int* in_sizes, int n_in,
                              void* d_out, int out_size, void* d_ws, size_t ws_size,
                              hipStream_t stream) {
    const float* pos = (const float*)d_in[0];
    // d_in[1] = rgb (unused), d_in[2] = batch (all zeros),
    // d_in[3] = out_index (= repeat(arange(N),K) by construction)
    const int* idx = (const int*)d_in[4];   // in_index, delivered as int32
    const float* w1a = (const float*)d_in[5];
    const float* b1a = (const float*)d_in[6];
    const float* w1b = (const float*)d_in[7];
    const float* b1b = (const float*)d_in[8];
    const float* w2a = (const float*)d_in[9];
    const float* b2a = (const float*)d_in[10];
    const float* w2b = (const float*)d_in[11];
    const float* b2b = (const float*)d_in[12];
    const float* w3a = (const float*)d_in[13];
    const float* b3a = (const float*)d_in[14];
    const float* w3b = (const float*)d_in[15];
    const float* b3b = (const float*)d_in[16];
    float* out = (float*)d_out;

    char* ws = (char*)d_ws;
    float* A = (float*)ws;                             // 8 MB: Q buffers (<= N x 32 f32)
    float* B = (float*)(ws + 8u * 1024u * 1024u);      // 8 MB: segment-max buffers

    // layer 1
    k_prep1<<<NPTS / 256, 256, 0, stream>>>(pos, w1a, b1a, A, out, out_size);
    k_edge<8><<<NPTS * 8 / 256, 256, 0, stream>>>(A, idx, B);
    k_finish<8, 8, 16, false><<<NPTS / 256, 256, 0, stream>>>(
        B, pos, w1a + 3 * 8, w1b, b1b, w2a, b2a, nullptr, A);
    // layer 2
    k_edge<16><<<NPTS * 8 / 256, 256, 0, stream>>>(A, idx, B);
    k_finish<16, 16, 32, false><<<NPTS / 256, 256, 0, stream>>>(
        B, pos, w2a + 8 * 16, w2b, b2b, w3a, b3a, nullptr, A);
    // layer 3
    k_edge<32><<<NPTS * 8 / 256, 256, 0, stream>>>(A, idx, B);
    k_finish<32, 32, 0, true><<<NPTS / 256, 256, 0, stream>>>(
        B, pos, w3a + 16 * 32, w3b, b3b, nullptr, nullptr, out + 3 * NPTS, nullptr);
}

// Round 3
// 210.945 us; speedup vs baseline: 1.5132x; 1.5132x over previous
//
#include <hip/hip_runtime.h>
#include <hip/hip_fp16.h>
#include <math.h>

// SPAIRPointFeatureNetwork on MI355X.
// Algebraic restructure: for each layer,
//   h_{p,j} = msg @ wa + ba = Q[j] - G[p],  Q[j]=x_j@wa_x + pos_j@wa_p + ba, G[p]=pos_p@wa_p
// celu monotonic => segment_max(celu(h)) = celu(max_j Q[j] - G[p]).
// Per-edge work = gather Q row + running max; all matmuls are O(N) precomputes.
//
// R2 post-mortem: k_edge<32> FETCH_SIZE ~280 MB/dispatch = L2 capacity thrash
// (537 MB logical gather vs 8 MB fp32 table > 4 MB per-XCD L2 -> ~50% miss).
// R3: Q tables in fp16 -> bytes/requests halve AND table fits one XCD's L2.
// Max done in fp32 after cvt (VALU was 4.9% busy -> conversion cost is free).

#define NPTS 65536
#define KNBR 64

__device__ __forceinline__ float celu1(float x) {
    return x > 0.0f ? x : (__expf(x) - 1.0f);
}

__device__ __forceinline__ void max2(float& a, float& b, unsigned u) {
    __half2 h = *(__half2*)&u;
    float2 f = __half22float2(h);
    a = fmaxf(a, f.x);
    b = fmaxf(b, f.y);
}

__device__ __forceinline__ unsigned pack2(float a, float b) {
    __half2 h = __floats2half2_rn(a, b);
    return *(unsigned*)&h;
}

// Kernel 1: compute Q1 (fp16) from pos, copy pos to d_out, zero batch tail.
__global__ __launch_bounds__(256) void k_prep1(
    const float* __restrict__ pos,
    const float* __restrict__ w1a,   // 6 x 8
    const float* __restrict__ b1a,   // 8
    __half* __restrict__ q1,         // N x 8 (fp16)
    float* __restrict__ dout,
    int out_size)
{
    int t = blockIdx.x * 256 + threadIdx.x;
    if (t >= NPTS) return;
    float p0 = pos[3 * t + 0];
    float p1 = pos[3 * t + 1];
    float p2 = pos[3 * t + 2];
    dout[3 * t + 0] = p0;
    dout[3 * t + 1] = p1;
    dout[3 * t + 2] = p2;
    float q[8];
#pragma unroll
    for (int c = 0; c < 8; ++c) {
        float a = b1a[c];
        a = fmaf(p0, w1a[0 * 8 + c] + w1a[3 * 8 + c], a);
        a = fmaf(p1, w1a[1 * 8 + c] + w1a[4 * 8 + c], a);
        a = fmaf(p2, w1a[2 * 8 + c] + w1a[5 * 8 + c], a);
        q[c] = a;
    }
    uint4 pk;
    pk.x = pack2(q[0], q[1]);
    pk.y = pack2(q[2], q[3]);
    pk.z = pack2(q[4], q[5]);
    pk.w = pack2(q[6], q[7]);
    *(uint4*)(q1 + 8 * t) = pk;
    // batch output (zeros) tail
    for (int j = 35 * NPTS + t; j < out_size; j += NPTS)
        dout[j] = 0.0f;
}

// Edge kernel: per point, max over 64 gathered fp16 Q rows. 8 threads/point
// (8192 waves -> 8 waves/SIMD) to hide gather latency. Output m is fp32.
template <int FH>
__global__ __launch_bounds__(256) void k_edge(
    const __half* __restrict__ q,   // N x FH (fp16)
    const int* __restrict__ idx,    // N x 64 (int32)
    float* __restrict__ m)          // N x FH (fp32 segment max)
{
    int gt = blockIdx.x * 256 + threadIdx.x;
    int p = gt >> 3;
    int s = gt & 7;
    float mx[FH];
#pragma unroll
    for (int c = 0; c < FH; ++c) mx[c] = -3.0e38f;

    int base = p * KNBR + s;
#pragma unroll 2
    for (int e = 0; e < KNBR / 8; ++e) {
        int j = idx[base + e * 8];
        const uint4* qr = (const uint4*)(q + j * FH);  // row = FH*2 bytes, 16B-aligned
#pragma unroll
        for (int l = 0; l < FH / 8; ++l) {
            uint4 v = qr[l];
            max2(mx[l * 8 + 0], mx[l * 8 + 1], v.x);
            max2(mx[l * 8 + 2], mx[l * 8 + 3], v.y);
            max2(mx[l * 8 + 4], mx[l * 8 + 5], v.z);
            max2(mx[l * 8 + 6], mx[l * 8 + 7], v.w);
        }
    }
    // butterfly max across the 8 slices of this point
#pragma unroll
    for (int st = 1; st < 8; st <<= 1) {
#pragma unroll
        for (int c = 0; c < FH; ++c)
            mx[c] = fmaxf(mx[c], __shfl_xor(mx[c], st, 64));
    }
    // slice s stores channels [s*CW,(s+1)*CW) — compile-time mux to avoid spill
    constexpr int CW = FH / 8;
    float outv[CW];
#pragma unroll
    for (int c = 0; c < CW; ++c) {
        float v = mx[c];
#pragma unroll
        for (int g = 1; g < 8; ++g)
            v = (s == g) ? mx[g * CW + c] : v;
        outv[c] = v;
    }
    float* dst = m + p * FH + s * CW;
    if constexpr (CW == 4) {
        *(float4*)dst = make_float4(outv[0], outv[1], outv[2], outv[3]);
    } else if constexpr (CW == 2) {
        *(float2*)dst = make_float2(outv[0], outv[1]);
    } else {
        *dst = outv[0];
    }
}

// Finish kernel: agg = celu(m - G), x = celu(agg@wb + bb); optionally emit
// next layer's Q (fp16, fused so x never hits memory except the final layer).
template <int FH, int FOUT, int FHN, bool WRITEX>
__global__ __launch_bounds__(256) void k_finish(
    const float* __restrict__ m,     // N x FH (fp32)
    const float* __restrict__ pos,
    const float* __restrict__ wap,   // 3 x FH  (dpos rows of this layer's wa)
    const float* __restrict__ wb,    // FH x FOUT
    const float* __restrict__ bb,    // FOUT
    const float* __restrict__ wan,   // (FOUT+3) x FHN (next layer wa) or null
    const float* __restrict__ ban,   // FHN or null
    float* __restrict__ xout,        // N x FOUT (only if WRITEX)
    __half* __restrict__ qnext)      // N x FHN fp16 (only if FHN>0)
{
    int t = blockIdx.x * 256 + threadIdx.x;
    float p0 = pos[3 * t + 0];
    float p1 = pos[3 * t + 1];
    float p2 = pos[3 * t + 2];

    float h[FH];
    const float4* mr = (const float4*)(m + t * FH);
#pragma unroll
    for (int c4 = 0; c4 < FH / 4; ++c4) {
        float4 v = mr[c4];
        h[4 * c4 + 0] = v.x;
        h[4 * c4 + 1] = v.y;
        h[4 * c4 + 2] = v.z;
        h[4 * c4 + 3] = v.w;
    }
#pragma unroll
    for (int c = 0; c < FH; ++c) {
        float g = p0 * wap[c] + p1 * wap[FH + c] + p2 * wap[2 * FH + c];
        h[c] = celu1(h[c] - g);
    }
    float x[FOUT];
#pragma unroll
    for (int c2 = 0; c2 < FOUT; ++c2) {
        float a = bb[c2];
#pragma unroll
        for (int c = 0; c < FH; ++c)
            a = fmaf(h[c], wb[c * FOUT + c2], a);
        x[c2] = celu1(a);
    }
    if constexpr (WRITEX) {
        float4* xo = (float4*)(xout + t * FOUT);
#pragma unroll
        for (int c4 = 0; c4 < FOUT / 4; ++c4)
            xo[c4] = make_float4(x[4 * c4 + 0], x[4 * c4 + 1], x[4 * c4 + 2], x[4 * c4 + 3]);
    }
    if constexpr (FHN > 0) {
        float qn[FHN];
#pragma unroll
        for (int cn = 0; cn < FHN; ++cn) {
            float a = ban[cn];
#pragma unroll
            for (int c2 = 0; c2 < FOUT; ++c2)
                a = fmaf(x[c2], wan[c2 * FHN + cn], a);
            a = fmaf(p0, wan[(FOUT + 0) * FHN + cn], a);
            a = fmaf(p1, wan[(FOUT + 1) * FHN + cn], a);
            a = fmaf(p2, wan[(FOUT + 2) * FHN + cn], a);
            qn[cn] = a;
        }
        uint4* qo = (uint4*)(qnext + t * FHN);
#pragma unroll
        for (int l = 0; l < FHN / 8; ++l) {
            uint4 pk;
            pk.x = pack2(qn[l * 8 + 0], qn[l * 8 + 1]);
            pk.y = pack2(qn[l * 8 + 2], qn[l * 8 + 3]);
            pk.z = pack2(qn[l * 8 + 4], qn[l * 8 + 5]);
            pk.w = pack2(qn[l * 8 + 6], qn[l * 8 + 7]);
            qo[l] = pk;
        }
    }
}

extern "C" void kernel_launch(void* const* d_in, const int* in_sizes, int n_in,
                              void* d_out, int out_size, void* d_ws, size_t ws_size,
                              hipStream_t stream) {
    const float* pos = (const float*)d_in[0];
    // d_in[1] = rgb (unused), d_in[2] = batch (zeros),
    // d_in[3] = out_index (= repeat(arange(N),K) by construction)
    const int* idx = (const int*)d_in[4];   // in_index, delivered as int32
    const float* w1a = (const float*)d_in[5];
    const float* b1a = (const float*)d_in[6];
    const float* w1b = (const float*)d_in[7];
    const float* b1b = (const float*)d_in[8];
    const float* w2a = (const float*)d_in[9];
    const float* b2a = (const float*)d_in[10];
    const float* w2b = (const float*)d_in[11];
    const float* b2b = (const float*)d_in[12];
    const float* w3a = (const float*)d_in[13];
    const float* b3a = (const float*)d_in[14];
    const float* w3b = (const float*)d_in[15];
    const float* b3b = (const float*)d_in[16];
    float* out = (float*)d_out;

    char* ws = (char*)d_ws;
    __half* A = (__half*)ws;                        // 4 MB: fp16 Q tables (<= N x 32)
    float*  B = (float*)(ws + 8u * 1024u * 1024u);  // 8 MB: fp32 segment-max buffers

    // layer 1
    k_prep1<<<NPTS / 256, 256, 0, stream>>>(pos, w1a, b1a, A, out, out_size);
    k_edge<8><<<NPTS * 8 / 256, 256, 0, stream>>>(A, idx, B);
    k_finish<8, 8, 16, false><<<NPTS / 256, 256, 0, stream>>>(
        B, pos, w1a + 3 * 8, w1b, b1b, w2a, b2a, nullptr, A);
    // layer 2
    k_edge<16><<<NPTS * 8 / 256, 256, 0, stream>>>(A, idx, B);
    k_finish<16, 16, 32, false><<<NPTS / 256, 256, 0, stream>>>(
        B, pos, w2a + 8 * 16, w2b, b2b, w3a, b3a, nullptr, A);
    // layer 3
    k_edge<32><<<NPTS * 8 / 256, 256, 0, stream>>>(A, idx, B);
    k_finish<32, 32, 0, true><<<NPTS / 256, 256, 0, stream>>>(
        B, pos, w3a + 16 * 32, w3b, b3b, nullptr, nullptr, out + 3 * NPTS, nullptr);
}

// Round 4
// 193.853 us; speedup vs baseline: 1.6466x; 1.0882x over previous
//
#include <hip/hip_runtime.h>
#include <hip/hip_fp16.h>
#include <math.h>

// SPAIRPointFeatureNetwork on MI355X.
//   h_{p,j} = Q[j] - G[p];  celu monotonic => segmax(celu(h)) = celu(max_j Q[j] - G[p]).
// Per-edge work = gather fp16 Q row + packed-fp16 running max.
//
// R3 post-mortem: edge kernels TA-bound — each 16B lane-request from a random
// row is its own L1 segment lookup (64 scattered lookups/instr). R4: 4 lanes
// cooperatively load one 64B row (FH=32) -> coalesces to 1 segment lookup per
// row; idx reads become contiguous uint4 preloads; max via v_pk_max_f16.

#define NPTS 65536
#define KNBR 64

__device__ __forceinline__ float celu1(float x) {
    return x > 0.0f ? x : (__expf(x) - 1.0f);
}

__device__ __forceinline__ unsigned pkmax(unsigned a, unsigned b) {
    unsigned d;
    asm("v_pk_max_f16 %0, %1, %2" : "=v"(d) : "v"(a), "v"(b));
    return d;
}

__device__ __forceinline__ unsigned pack2(float a, float b) {
    __half2 h = __floats2half2_rn(a, b);
    return *(unsigned*)&h;
}

// Kernel 1: compute Q1 (fp16) from pos, copy pos to d_out, zero batch tail.
__global__ __launch_bounds__(256) void k_prep1(
    const float* __restrict__ pos,
    const float* __restrict__ w1a,   // 6 x 8
    const float* __restrict__ b1a,   // 8
    __half* __restrict__ q1,         // N x 8 (fp16)
    float* __restrict__ dout,
    int out_size)
{
    int t = blockIdx.x * 256 + threadIdx.x;
    if (t >= NPTS) return;
    float p0 = pos[3 * t + 0];
    float p1 = pos[3 * t + 1];
    float p2 = pos[3 * t + 2];
    dout[3 * t + 0] = p0;
    dout[3 * t + 1] = p1;
    dout[3 * t + 2] = p2;
    float q[8];
#pragma unroll
    for (int c = 0; c < 8; ++c) {
        float a = b1a[c];
        a = fmaf(p0, w1a[0 * 8 + c] + w1a[3 * 8 + c], a);
        a = fmaf(p1, w1a[1 * 8 + c] + w1a[4 * 8 + c], a);
        a = fmaf(p2, w1a[2 * 8 + c] + w1a[5 * 8 + c], a);
        q[c] = a;
    }
    uint4 pk;
    pk.x = pack2(q[0], q[1]);
    pk.y = pack2(q[2], q[3]);
    pk.z = pack2(q[4], q[5]);
    pk.w = pack2(q[6], q[7]);
    *(uint4*)(q1 + 8 * t) = pk;
    for (int j = 35 * NPTS + t; j < out_size; j += NPTS)
        dout[j] = 0.0f;
}

// Edge kernel, row-parallel: wave = 4 points x 16 lanes. Within a point,
// SL = FH/8 lanes cooperatively hold one row (16B slice each, coalescing to
// one 64B segment for FH=32), EG = 16/SL edge-groups run in parallel, each
// group scanning EPG = 64/EG contiguous edges (so idx preloads are uint4s).
// Max in packed fp16 (exact). Output m in fp16 (lossless: values are table
// entries).
template <int FH>
__global__ __launch_bounds__(256) void k_edge(
    const __half* __restrict__ q,   // N x FH (fp16)
    const int* __restrict__ idx,    // N x 64 (int32)
    __half* __restrict__ m)         // N x FH (fp16 segment max)
{
    constexpr int SL  = FH / 8;     // lanes per row
    constexpr int EG  = 16 / SL;    // edge groups per point
    constexpr int EPG = 64 / EG;    // edges per group (contiguous)

    int wave = (blockIdx.x * 256 + threadIdx.x) >> 6;
    int l  = threadIdx.x & 63;
    int pl = l >> 4;
    int u  = l & 15;
    int c  = u % SL;                // 16B slice within row
    int g  = u / SL;                // edge group
    int p  = wave * 4 + pl;

    // contiguous idx preload for this lane's edge group
    const uint4* ip = (const uint4*)(idx + p * KNBR + g * EPG);
    uint4 iv[EPG / 4];
#pragma unroll
    for (int k = 0; k < EPG / 4; ++k) iv[k] = ip[k];

    unsigned ax = 0xFC00FC00u, ay = 0xFC00FC00u, az = 0xFC00FC00u, aw = 0xFC00FC00u;
#pragma unroll
    for (int k = 0; k < EPG / 4; ++k) {
        int j0 = (int)iv[k].x, j1 = (int)iv[k].y, j2 = (int)iv[k].z, j3 = (int)iv[k].w;
        uint4 v0 = *(const uint4*)(q + j0 * FH + c * 8);
        uint4 v1 = *(const uint4*)(q + j1 * FH + c * 8);
        uint4 v2 = *(const uint4*)(q + j2 * FH + c * 8);
        uint4 v3 = *(const uint4*)(q + j3 * FH + c * 8);
        ax = pkmax(ax, v0.x); ay = pkmax(ay, v0.y); az = pkmax(az, v0.z); aw = pkmax(aw, v0.w);
        ax = pkmax(ax, v1.x); ay = pkmax(ay, v1.y); az = pkmax(az, v1.z); aw = pkmax(aw, v1.w);
        ax = pkmax(ax, v2.x); ay = pkmax(ay, v2.y); az = pkmax(az, v2.z); aw = pkmax(aw, v2.w);
        ax = pkmax(ax, v3.x); ay = pkmax(ay, v3.y); az = pkmax(az, v3.z); aw = pkmax(aw, v3.w);
    }
    // butterfly max across edge groups (strides SL..8 stay within the 16-lane point)
#pragma unroll
    for (int st = SL; st < 16; st <<= 1) {
        ax = pkmax(ax, (unsigned)__shfl_xor((int)ax, st, 64));
        ay = pkmax(ay, (unsigned)__shfl_xor((int)ay, st, 64));
        az = pkmax(az, (unsigned)__shfl_xor((int)az, st, 64));
        aw = pkmax(aw, (unsigned)__shfl_xor((int)aw, st, 64));
    }
    if (g == 0) {
        uint4 r; r.x = ax; r.y = ay; r.z = az; r.w = aw;
        *(uint4*)(m + p * FH + c * 8) = r;
    }
}

// Finish: agg = celu(m - G), x = celu(agg@wb + bb); optionally emit next Q (fp16).
template <int FH, int FOUT, int FHN, bool WRITEX>
__global__ __launch_bounds__(256) void k_finish(
    const __half* __restrict__ m,    // N x FH (fp16)
    const float* __restrict__ pos,
    const float* __restrict__ wap,   // 3 x FH  (dpos rows of this layer's wa)
    const float* __restrict__ wb,    // FH x FOUT
    const float* __restrict__ bb,    // FOUT
    const float* __restrict__ wan,   // (FOUT+3) x FHN or null
    const float* __restrict__ ban,   // FHN or null
    float* __restrict__ xout,        // N x FOUT (only if WRITEX)
    __half* __restrict__ qnext)      // N x FHN fp16 (only if FHN>0)
{
    int t = blockIdx.x * 256 + threadIdx.x;
    float p0 = pos[3 * t + 0];
    float p1 = pos[3 * t + 1];
    float p2 = pos[3 * t + 2];

    float h[FH];
    const uint4* mr = (const uint4*)(m + t * FH);
#pragma unroll
    for (int l = 0; l < FH / 8; ++l) {
        uint4 v = mr[l];
        unsigned w4[4] = {v.x, v.y, v.z, v.w};
#pragma unroll
        for (int k = 0; k < 4; ++k) {
            float2 f = __half22float2(*(__half2*)&w4[k]);
            h[l * 8 + k * 2 + 0] = f.x;
            h[l * 8 + k * 2 + 1] = f.y;
        }
    }
#pragma unroll
    for (int c = 0; c < FH; ++c) {
        float g = p0 * wap[c] + p1 * wap[FH + c] + p2 * wap[2 * FH + c];
        h[c] = celu1(h[c] - g);
    }
    float x[FOUT];
#pragma unroll
    for (int c2 = 0; c2 < FOUT; ++c2) {
        float a = bb[c2];
#pragma unroll
        for (int c = 0; c < FH; ++c)
            a = fmaf(h[c], wb[c * FOUT + c2], a);
        x[c2] = celu1(a);
    }
    if constexpr (WRITEX) {
        float4* xo = (float4*)(xout + t * FOUT);
#pragma unroll
        for (int c4 = 0; c4 < FOUT / 4; ++c4)
            xo[c4] = make_float4(x[4 * c4 + 0], x[4 * c4 + 1], x[4 * c4 + 2], x[4 * c4 + 3]);
    }
    if constexpr (FHN > 0) {
        float qn[FHN];
#pragma unroll
        for (int cn = 0; cn < FHN; ++cn) {
            float a = ban[cn];
#pragma unroll
            for (int c2 = 0; c2 < FOUT; ++c2)
                a = fmaf(x[c2], wan[c2 * FHN + cn], a);
            a = fmaf(p0, wan[(FOUT + 0) * FHN + cn], a);
            a = fmaf(p1, wan[(FOUT + 1) * FHN + cn], a);
            a = fmaf(p2, wan[(FOUT + 2) * FHN + cn], a);
            qn[cn] = a;
        }
        uint4* qo = (uint4*)(qnext + t * FHN);
#pragma unroll
        for (int l = 0; l < FHN / 8; ++l) {
            uint4 pk;
            pk.x = pack2(qn[l * 8 + 0], qn[l * 8 + 1]);
            pk.y = pack2(qn[l * 8 + 2], qn[l * 8 + 3]);
            pk.z = pack2(qn[l * 8 + 4], qn[l * 8 + 5]);
            pk.w = pack2(qn[l * 8 + 6], qn[l * 8 + 7]);
            qo[l] = pk;
        }
    }
}

extern "C" void kernel_launch(void* const* d_in, const int* in_sizes, int n_in,
                              void* d_out, int out_size, void* d_ws, size_t ws_size,
                              hipStream_t stream) {
    const float* pos = (const float*)d_in[0];
    // d_in[1] rgb (unused), d_in[2] batch (zeros), d_in[3] out_index (= repeat(arange(N),K))
    const int* idx = (const int*)d_in[4];   // in_index, int32 per harness contract
    const float* w1a = (const float*)d_in[5];
    const float* b1a = (const float*)d_in[6];
    const float* w1b = (const float*)d_in[7];
    const float* b1b = (const float*)d_in[8];
    const float* w2a = (const float*)d_in[9];
    const float* b2a = (const float*)d_in[10];
    const float* w2b = (const float*)d_in[11];
    const float* b2b = (const float*)d_in[12];
    const float* w3a = (const float*)d_in[13];
    const float* b3a = (const float*)d_in[14];
    const float* w3b = (const float*)d_in[15];
    const float* b3b = (const float*)d_in[16];
    float* out = (float*)d_out;

    char* ws = (char*)d_ws;
    __half* A = (__half*)ws;                          // 4 MB max: fp16 Q tables
    __half* B = (__half*)(ws + 8u * 1024u * 1024u);   // 4 MB max: fp16 segmax

    // layer 1
    k_prep1<<<NPTS / 256, 256, 0, stream>>>(pos, w1a, b1a, A, out, out_size);
    k_edge<8><<<NPTS / 16, 256, 0, stream>>>(A, idx, B);
    k_finish<8, 8, 16, false><<<NPTS / 256, 256, 0, stream>>>(
        B, pos, w1a + 3 * 8, w1b, b1b, w2a, b2a, nullptr, A);
    // layer 2
    k_edge<16><<<NPTS / 16, 256, 0, stream>>>(A, idx, B);
    k_finish<16, 16, 32, false><<<NPTS / 256, 256, 0, stream>>>(
        B, pos, w2a + 8 * 16, w2b, b2b, w3a, b3a, nullptr, A);
    // layer 3
    k_edge<32><<<NPTS / 16, 256, 0, stream>>>(A, idx, B);
    k_finish<32, 32, 0, true><<<NPTS / 256, 256, 0, stream>>>(
        B, pos, w3a + 16 * 32, w3b, b3b, nullptr, nullptr, out + 3 * NPTS, nullptr);
}